// Round 5
// baseline (1882.654 us; speedup 1.0000x reference)
//
#include <hip/hip_runtime.h>
#include <cstdint>
#include <cstring>

typedef _Float16 f16;
typedef _Float16 f16x8 __attribute__((ext_vector_type(8)));
typedef float f32x4 __attribute__((ext_vector_type(4)));

// ---- JAX threefry scheme: 1 = partitionable (jax >= 0.4.36 default), 0 = original
static constexpr int kPartitionable = 1;

struct Ptr8 { const float* p[8]; };
struct Keys8 { uint32_t k[8][2]; };

// Swizzled storage for f16 hi/lo GEMM operands:
//   element (row r, col k) lives at physical k ^ ((r&7)<<3)
// (16B-chunk permutation within each aligned 128B group) -> lane-ordered
// global_load_lds staging + conflict-uniform LDS fragment reads.
__device__ __host__ __forceinline__ int swz(int r, int k) {
  return k ^ ((r & 7) << 3);
}

// async 16B global -> LDS (no VGPR roundtrip); dest = ldsbase + lane*16
__device__ __forceinline__ void gload16(const void* g, void* l) {
  __builtin_amdgcn_global_load_lds(
      (const __attribute__((address_space(1))) unsigned int*)g,
      (__attribute__((address_space(3))) unsigned int*)l, 16, 0, 0);
}

// ---------------- Threefry-2x32 (host + device) ----------------
__host__ __device__ inline void tf2x32(uint32_t k0, uint32_t k1,
                                       uint32_t x0, uint32_t x1,
                                       uint32_t& o0, uint32_t& o1) {
  uint32_t ks[3] = {k0, k1, k0 ^ k1 ^ 0x1BD11BDAu};
  uint32_t v0 = x0 + ks[0], v1 = x1 + ks[1];
  const int r0[4] = {13, 15, 26, 6};
  const int r1[4] = {17, 29, 16, 24};
  for (int g = 0; g < 5; ++g) {
    const int* rr = (g & 1) ? r1 : r0;
    for (int j = 0; j < 4; ++j) {
      v0 += v1;
      v1 = (v1 << rr[j]) | (v1 >> (32 - rr[j]));
      v1 ^= v0;
    }
    v0 += ks[(g + 1) % 3];
    v1 += ks[(g + 2) % 3] + (uint32_t)(g + 1);
  }
  o0 = v0; o1 = v1;
}

// ---------------- split-fp16 MFMA GEMM (encoder/LSTM path) ----------------
template <int BM, int BN>
__global__ __launch_bounds__(256, 2) void gemm_split(
    const f16* __restrict__ Ah, const f16* __restrict__ Al, int lda,
    const f16* __restrict__ Bh, const f16* __restrict__ Bl, int ldb,
    int K,
    const float* __restrict__ bias1, const float* __restrict__ bias2,
    int nReal, int relu, int writeF32,
    float* __restrict__ outF, f16* __restrict__ outH, f16* __restrict__ outL,
    int ldo) {
  constexpr int BK = 64;
  constexpr int TM = BM / 32;
  constexpr int TN = BN / 32;
  static_assert(BM == BN, "square tiles only");
  __shared__ f16 sAh[BM * BK];
  __shared__ f16 sAl[BM * BK];
  __shared__ f16 sBh[BN * BK];
  __shared__ f16 sBl[BN * BK];

  const int tid = threadIdx.x;
  const int wave = tid >> 6;
  const int lane = tid & 63;
  const int wm = wave & 1, wn = wave >> 1;
  const int m0 = blockIdx.x * BM;
  const int n0 = blockIdx.y * BN;

  f32x4 acc[TM][TN];
  const f32x4 zero = {0.f, 0.f, 0.f, 0.f};
#pragma unroll
  for (int i = 0; i < TM; ++i)
#pragma unroll
    for (int j = 0; j < TN; ++j) acc[i][j] = zero;

  const f16* src;
  f16* dst;
  int ld, base;
  if (wave == 0)      { src = Ah; dst = sAh; ld = lda; base = m0; }
  else if (wave == 1) { src = Al; dst = sAl; ld = lda; base = m0; }
  else if (wave == 2) { src = Bh; dst = sBh; ld = ldb; base = n0; }
  else                { src = Bl; dst = sBl; ld = ldb; base = n0; }
  constexpr int NITER = BM / 8;
  const f16* gbase = src + (size_t)(base + (lane >> 3)) * ld + (lane & 7) * 8;

  const int fr = lane & 15;
  const int q8 = (lane >> 4) * 8;
  const int sw = (fr & 7) << 3;

  for (int k0 = 0; k0 < K; k0 += BK) {
    __syncthreads();
#pragma unroll
    for (int j = 0; j < NITER; ++j)
      gload16(gbase + (size_t)(j * 8) * ld + k0, dst + j * 512);
    __syncthreads();
#pragma unroll
    for (int kk = 0; kk < BK; kk += 32) {
      const int kf = (kk + q8) ^ sw;
      f16x8 aH[TM], aL[TM], bH[TN], bL[TN];
#pragma unroll
      for (int i = 0; i < TM; ++i) {
        int off = (wm * (BM / 2) + i * 16 + fr) * BK + kf;
        aH[i] = *(const f16x8*)&sAh[off];
        aL[i] = *(const f16x8*)&sAl[off];
      }
#pragma unroll
      for (int j = 0; j < TN; ++j) {
        int off = (wn * (BN / 2) + j * 16 + fr) * BK + kf;
        bH[j] = *(const f16x8*)&sBh[off];
        bL[j] = *(const f16x8*)&sBl[off];
      }
#pragma unroll
      for (int i = 0; i < TM; ++i)
#pragma unroll
        for (int j = 0; j < TN; ++j) {
          acc[i][j] = __builtin_amdgcn_mfma_f32_16x16x32_f16(aH[i], bH[j], acc[i][j], 0, 0, 0);
          acc[i][j] = __builtin_amdgcn_mfma_f32_16x16x32_f16(aH[i], bL[j], acc[i][j], 0, 0, 0);
          acc[i][j] = __builtin_amdgcn_mfma_f32_16x16x32_f16(aL[i], bH[j], acc[i][j], 0, 0, 0);
        }
    }
  }
  const int rq = lane >> 4, cl = lane & 15;
#pragma unroll
  for (int i = 0; i < TM; ++i)
#pragma unroll
    for (int j = 0; j < TN; ++j)
#pragma unroll
      for (int r = 0; r < 4; ++r) {
        int row = m0 + wm * (BM / 2) + i * 16 + rq * 4 + r;
        int col = n0 + wn * (BN / 2) + j * 16 + cl;
        float v = acc[i][j][r];
        if (col < nReal) {
          if (bias1) v += bias1[col];
          if (bias2) v += bias2[col];
          if (relu) v = fmaxf(v, 0.f);
        } else {
          v = 0.f;
        }
        if (writeF32) {
          outF[(size_t)row * ldo + col] = v;
        } else {
          size_t o = (size_t)row * ldo + swz(row, col);
          f16 h = (f16)v;
          outH[o] = h;
          outL[o] = (f16)(v - (float)h);
        }
      }
}

// ---------------- conversion kernels ----------------
// feats -> hi/lo fp16 [4096][9280] swizzled; one 16B chunk (8 cols) per thread
__global__ void conv_feats(const float* __restrict__ A, const float* __restrict__ O,
                           const float* __restrict__ LA, const int* __restrict__ EP,
                           f16* __restrict__ H, f16* __restrict__ L) {
  uint32_t idx = blockIdx.x * 256u + threadIdx.x;  // 4096 * 1160 chunks
  if (idx >= 4096u * 1160u) return;
  uint32_t b = idx / 1160u;
  uint32_t c = (idx - b * 1160u) * 8u;
  float v[8];
  if (c < 4608u) {
    const float4* p = (const float4*)(A + (size_t)b * 4608 + c);
    float4 x = p[0], y = p[1];
    v[0] = x.x; v[1] = x.y; v[2] = x.z; v[3] = x.w;
    v[4] = y.x; v[5] = y.y; v[6] = y.z; v[7] = y.w;
  } else if (c < 9216u) {
    const float4* p = (const float4*)(O + (size_t)b * 4608 + (c - 4608u));
    float4 x = p[0], y = p[1];
    v[0] = x.x; v[1] = x.y; v[2] = x.z; v[3] = x.w;
    v[4] = y.x; v[5] = y.y; v[6] = y.z; v[7] = y.w;
  } else if (c == 9216u) {
#pragma unroll
    for (int j = 0; j < 8; ++j) v[j] = LA[(size_t)b * 8 + j];
  } else if (c == 9224u) {
    v[0] = (float)EP[0];
#pragma unroll
    for (int j = 1; j < 8; ++j) v[j] = 0.f;
  } else {
#pragma unroll
    for (int j = 0; j < 8; ++j) v[j] = 0.f;
  }
  size_t o = (size_t)b * 9280 + ((int)c ^ (((int)b & 7) << 3));
  f16x8 hv, lv;
#pragma unroll
  for (int j = 0; j < 8; ++j) {
    f16 h = (f16)v[j];
    hv[j] = h;
    lv[j] = (f16)(v[j] - (float)h);
  }
  *(f16x8*)&H[o] = hv;
  *(f16x8*)&L[o] = lv;
}

// W [Kreal][Nreal] -> Bt hi/lo [Npad][Kpad] swizzled, Bt[n][k]=W[k][n]
__global__ void convT_kernel(const float* __restrict__ W, int Kreal, int Nreal,
                             f16* __restrict__ BtH, f16* __restrict__ BtL, int Kpad) {
  __shared__ float tile[32][33];
  int k0 = blockIdx.x * 32, n0 = blockIdx.y * 32;
  int tx = threadIdx.x, ty = threadIdx.y;  // 32 x 8
  for (int r = 0; r < 32; r += 8) {
    int k = k0 + ty + r, n = n0 + tx;
    float v = (k < Kreal && n < Nreal) ? W[(size_t)k * Nreal + n] : 0.f;
    tile[ty + r][tx] = v;
  }
  __syncthreads();
  for (int r = 0; r < 32; r += 8) {
    int n = n0 + ty + r, k = k0 + tx;
    float v = tile[tx][ty + r];
    size_t o = (size_t)n * Kpad + swz(n, k);
    f16 h = (f16)v;
    BtH[o] = h;
    BtL[o] = (f16)(v - (float)h);
  }
}

// W [Kreal][Nreal] -> fragment-major: FH[((ntile*KC+kc)*64+lane)*8 + j] =
//   hi(W[kc*32+(lane>>4)*8+j][ntile*16+(lane&15)])  (B-operand of 16x16x32 f16)
__global__ void conv_fm(const float* __restrict__ W, int Kreal, int Nreal, int NT, int KC,
                        f16* __restrict__ FH, f16* __restrict__ FL) {
  int idx = blockIdx.x * 256 + threadIdx.x;
  if (idx >= NT * KC * 64) return;
  int lane = idx & 63;
  int t = idx >> 6;
  int kc = t % KC, ntile = t / KC;
  int n = ntile * 16 + (lane & 15);
  int k0 = kc * 32 + (lane >> 4) * 8;
  f16x8 hv, lv;
#pragma unroll
  for (int j = 0; j < 8; ++j) {
    int k = k0 + j;
    float v = (k < Kreal && n < Nreal) ? W[(size_t)k * Nreal + n] : 0.f;
    f16 h = (f16)v;
    hv[j] = h;
    lv[j] = (f16)(v - (float)h);
  }
  *(f16x8*)&FH[(size_t)idx * 8] = hv;
  *(f16x8*)&FL[(size_t)idx * 8] = lv;
}

// all 8 head weights [256][64] -> fragment-major, base h*16384 f16
__global__ void conv_fm_heads(Ptr8 ws, f16* __restrict__ FH, f16* __restrict__ FL) {
  int h = blockIdx.y;
  int idx = blockIdx.x * 256 + threadIdx.x;  // 4*8*64 = 2048
  if (idx >= 2048) return;
  int lane = idx & 63;
  int t = idx >> 6;
  int kc = t & 7, ntile = t >> 3;
  int n = ntile * 16 + (lane & 15);
  int k0 = kc * 32 + (lane >> 4) * 8;
  const float* W = ws.p[h];
  f16x8 hv, lv;
#pragma unroll
  for (int j = 0; j < 8; ++j) {
    float v = W[(size_t)(k0 + j) * 64 + n];
    f16 hh = (f16)v;
    hv[j] = hh;
    lv[j] = (f16)(v - (float)hh);
  }
  size_t base = (size_t)h * 16384 + (size_t)idx * 8;
  *(f16x8*)&FH[base] = hv;
  *(f16x8*)&FL[base] = lv;
}

// Bt_lstm [2048][1024]: cols 0-511 = Wih row n, cols 512-1023 = Whh row n
__global__ void conv_lstmB(const float* __restrict__ Wih, const float* __restrict__ Whh,
                           f16* __restrict__ H, f16* __restrict__ L) {
  uint32_t idx = blockIdx.x * 256u + threadIdx.x;
  uint32_t n = idx >> 10, k = idx & 1023u;
  float v = (k < 512u) ? Wih[(size_t)n * 512 + k] : Whh[(size_t)n * 512 + (k - 512u)];
  size_t o = (size_t)n * 1024 + swz((int)n, (int)k);
  f16 h = (f16)v;
  H[o] = h;
  L[o] = (f16)(v - (float)h);
}

// h0 -> A_lstm cols 512..1023
__global__ void conv_h0(const float* __restrict__ h0, f16* __restrict__ H, f16* __restrict__ L) {
  uint32_t idx = blockIdx.x * 256u + threadIdx.x;
  uint32_t b = idx >> 9, j = idx & 511u;
  float v = h0[idx];
  size_t o = (size_t)b * 1024 + swz((int)b, (int)(512 + j));
  f16 h = (f16)v;
  H[o] = h;
  L[o] = (f16)(v - (float)h);
}

// LSTM pointwise -> z hi/lo into zA [4096][576] swizzled (cols 0..511)
__global__ void lstm_pointwise(const float* __restrict__ gates, const float* __restrict__ c0,
                               f16* __restrict__ zH, f16* __restrict__ zL) {
  uint32_t idx = blockIdx.x * 256u + threadIdx.x;
  uint32_t b = idx >> 9, n = idx & 511u;
  const float* g = gates + (size_t)b * 2048;
  float gi = g[n], gf = g[512 + n], gg = g[1024 + n], go = g[1536 + n];
  float si = 1.f / (1.f + expf(-gi));
  float sf = 1.f / (1.f + expf(-gf));
  float so = 1.f / (1.f + expf(-go));
  float c = sf * c0[idx] + si * tanhf(gg);
  float z = so * tanhf(c);
  size_t o = (size_t)b * 576 + swz((int)b, (int)n);
  f16 h = (f16)z;
  zH[o] = h;
  zL[o] = (f16)(z - (float)h);
}

// zero zA pad region (phys cols 512..575 of each row) + entropy slot
__global__ void init_pads(f16* __restrict__ zAH, f16* __restrict__ zAL,
                          float* __restrict__ out) {
  uint32_t idx = blockIdx.x * 256u + threadIdx.x;  // 4096 rows x 8 chunks
  if (idx < 4096u * 8u) {
    uint32_t b = idx >> 3, c8 = 512u + (idx & 7u) * 8u;
    f16x8 zz = {0, 0, 0, 0, 0, 0, 0, 0};
    *(f16x8*)&zAH[(size_t)b * 576 + c8] = zz;
    *(f16x8*)&zAL[(size_t)b * 576 + c8] = zz;
  }
  if (idx == 0) out[32768] = 0.f;
}

__device__ inline double shfl_xor_dbl(double v, int m) {
  union { double d; int i[2]; } u;
  u.d = v;
  u.i[0] = __shfl_xor(u.i[0], m);
  u.i[1] = __shfl_xor(u.i[1], m);
  return u.d;
}

// ---------------- fused autoregressive decoder (take 2) ----------------
// 128 blocks x 32 rows x 4 waves. z/z1/logits persist in LDS (114.7 KB,
// 1 block/CU). Weights read per-MFMA-fragment from global in fragment-major
// layout: 16B/lane fully-coalesced dwordx4, L2-resident, no LDS staging,
// 5 barriers/head. K-order + MFMA triple order identical to the multi-launch
// path -> bit-identical logits -> exact actions.
__global__ __launch_bounds__(256, 1) void decoder_fused(
    const f16* __restrict__ zH0, const f16* __restrict__ zL0,       // [4096][576] swz
    const f16* __restrict__ FM1h, const f16* __restrict__ FM1l,     // dW1 frag-major
    const float* __restrict__ db1,
    const f16* __restrict__ FMhh, const f16* __restrict__ FMhl,     // heads frag-major
    Ptr8 hb,
    const f16* __restrict__ FMoh, const f16* __restrict__ FMol,     // dWo frag-major
    const float* __restrict__ dbo,
    Keys8 sk, int partitionable, float* __restrict__ out) {
  constexpr int ZS = 576, Z1S = 256;
  __shared__ f16 zbH[32 * ZS], zbL[32 * ZS];    // 73728 B
  __shared__ f16 z1H[32 * Z1S], z1L[32 * Z1S];  // 32768 B
  __shared__ float lgt[32 * 64];                // 8192 B
  __shared__ float entSh[4];
  const int tid = threadIdx.x;
  const int wave = tid >> 6, lane = tid & 63;
  const int fr = lane & 15, rq = lane >> 4, q8 = rq * 8;
  const int sw = (fr & 7) << 3;
  const int b0 = blockIdx.x * 32;
  const f32x4 zero = {0.f, 0.f, 0.f, 0.f};

  // initial z load: straight chunk copy (layouts match), pads already zero
  for (int t = tid; t < 2304; t += 256) {
    ((f16x8*)zbH)[t] = ((const f16x8*)(zH0 + (size_t)b0 * ZS))[t];
    ((f16x8*)zbL)[t] = ((const f16x8*)(zL0 + (size_t)b0 * ZS))[t];
  }
  float entAcc = 0.f;
  float logpAcc[8] = {0.f, 0.f, 0.f, 0.f, 0.f, 0.f, 0.f, 0.f};

  for (int h = 0; h < 8; ++h) {
    __syncthreads();  // zb ready (initial copy or prev stage4)
    // ---- stage1: z1[32][256] = relu(z @ dW1 + db1); wave w -> cols w*64
    {
      f32x4 acc[2][4];
#pragma unroll
      for (int i = 0; i < 2; ++i)
#pragma unroll
        for (int j = 0; j < 4; ++j) acc[i][j] = zero;
      for (int kc = 0; kc < 16; ++kc) {
        int kf = (kc * 32 + q8) ^ sw;
        f16x8 aH[2], aL[2];
#pragma unroll
        for (int i = 0; i < 2; ++i) {
          int off = (i * 16 + fr) * ZS + kf;
          aH[i] = *(const f16x8*)&zbH[off];
          aL[i] = *(const f16x8*)&zbL[off];
        }
#pragma unroll
        for (int j = 0; j < 4; ++j) {
          size_t fo = (size_t)((wave * 4 + j) * 16 + kc) * 512 + lane * 8;
          f16x8 bH = *(const f16x8*)&FM1h[fo];
          f16x8 bL = *(const f16x8*)&FM1l[fo];
#pragma unroll
          for (int i = 0; i < 2; ++i) {
            acc[i][j] = __builtin_amdgcn_mfma_f32_16x16x32_f16(aH[i], bH, acc[i][j], 0, 0, 0);
            acc[i][j] = __builtin_amdgcn_mfma_f32_16x16x32_f16(aH[i], bL, acc[i][j], 0, 0, 0);
            acc[i][j] = __builtin_amdgcn_mfma_f32_16x16x32_f16(aL[i], bH, acc[i][j], 0, 0, 0);
          }
        }
      }
#pragma unroll
      for (int j = 0; j < 4; ++j) {
        int col = (wave * 4 + j) * 16 + fr;
        float bb = db1[col];
#pragma unroll
        for (int i = 0; i < 2; ++i)
#pragma unroll
          for (int r = 0; r < 4; ++r) {
            int row = i * 16 + rq * 4 + r;
            float v = fmaxf(acc[i][j][r] + bb, 0.f);
            f16 hv = (f16)v;
            int po = row * Z1S + (col ^ ((row & 7) << 3));
            z1H[po] = hv;
            z1L[po] = (f16)(v - (float)hv);
          }
      }
    }
    __syncthreads();
    // ---- stage2: logits[32][64] = z1 @ Wk + bk; wave -> rows (w&1)*16, cols (w>>1)*32
    {
      f32x4 acc2[2] = {zero, zero};
      const int r0 = (wave & 1) * 16;
      const int tb = (wave >> 1) * 2;
      for (int kc = 0; kc < 8; ++kc) {
        int kf = (kc * 32 + q8) ^ sw;
        int off = (r0 + fr) * Z1S + kf;
        f16x8 aH = *(const f16x8*)&z1H[off];
        f16x8 aL = *(const f16x8*)&z1L[off];
#pragma unroll
        for (int j = 0; j < 2; ++j) {
          size_t fo = (size_t)(h * 32 + (tb + j) * 8 + kc) * 512 + lane * 8;
          f16x8 bH = *(const f16x8*)&FMhh[fo];
          f16x8 bL = *(const f16x8*)&FMhl[fo];
          acc2[j] = __builtin_amdgcn_mfma_f32_16x16x32_f16(aH, bH, acc2[j], 0, 0, 0);
          acc2[j] = __builtin_amdgcn_mfma_f32_16x16x32_f16(aH, bL, acc2[j], 0, 0, 0);
          acc2[j] = __builtin_amdgcn_mfma_f32_16x16x32_f16(aL, bH, acc2[j], 0, 0, 0);
        }
      }
#pragma unroll
      for (int j = 0; j < 2; ++j) {
        int col = (tb + j) * 16 + fr;
        float bb = hb.p[h][col];
#pragma unroll
        for (int r = 0; r < 4; ++r) lgt[(r0 + rq * 4 + r) * 64 + col] = acc2[j][r] + bb;
      }
    }
    __syncthreads();
    // ---- stage3: sample rows wave*8 .. wave*8+7 (lane = category)
    for (int rr = 0; rr < 8; ++rr) {
      int row = wave * 8 + rr;
      int b = b0 + row;
      float l = lgt[row * 64 + lane];
      uint32_t i = (uint32_t)b * 64u + (uint32_t)lane;
      uint32_t bits;
      if (partitionable) {
        uint32_t o0, o1;
        tf2x32(sk.k[h][0], sk.k[h][1], 0u, i, o0, o1);
        bits = o0 ^ o1;
      } else {
        const uint32_t Hh = 131072u;
        uint32_t c0, c1, o0, o1;
        int pick;
        if (i < Hh) { c0 = i; c1 = i + Hh; pick = 0; }
        else        { c0 = i - Hh; c1 = i; pick = 1; }
        tf2x32(sk.k[h][0], sk.k[h][1], c0, c1, o0, o1);
        bits = pick ? o1 : o0;
      }
      uint32_t ub = (bits >> 9) | 0x3f800000u;
      float u;
      __builtin_memcpy(&u, &ub, 4);
      u -= 1.0f;
      if (u == 0.0f) u = 1.17549435e-38f;
      double gum = -log(-log((double)u));
      double s = (double)l + gum;
      int bi = lane;
      double bv = s;
#pragma unroll
      for (int off = 1; off < 64; off <<= 1) {
        double ov = shfl_xor_dbl(bv, off);
        int oi = __shfl_xor(bi, off);
        if (ov > bv || (ov == bv && oi < bi)) { bv = ov; bi = oi; }
      }
      int act = bi;
      float m = l;
#pragma unroll
      for (int off = 1; off < 64; off <<= 1) m = fmaxf(m, __shfl_xor(m, off));
      float e = expf(l - m);
      float S = e, D = e * l;
#pragma unroll
      for (int off = 1; off < 64; off <<= 1) {
        S += __shfl_xor(S, off);
        D += __shfl_xor(D, off);
      }
      float M = m + logf(S);
      entAcc += (M - D / S);
      float l_act = __shfl(l, act);
      logpAcc[rr] += (l_act - M);
      if (lane == 0) {
        out[(size_t)b * 8 + h] = (float)act;
        int po = row * ZS + (512 ^ ((row & 7) << 3));
        zbH[po] = (f16)act;  // act <= 63, exact in fp16
        zbL[po] = (f16)0.f;
      }
    }
    __syncthreads();
    // ---- stage4: z_new[32][512] = relu([z|act] @ dWo + dbo); wave w -> cols w*128
    {
      f32x4 acc4[2][8];
#pragma unroll
      for (int i = 0; i < 2; ++i)
#pragma unroll
        for (int j = 0; j < 8; ++j) acc4[i][j] = zero;
      for (int kc = 0; kc < 18; ++kc) {
        int kf = (kc * 32 + q8) ^ sw;
        f16x8 aH[2], aL[2];
#pragma unroll
        for (int i = 0; i < 2; ++i) {
          int off = (i * 16 + fr) * ZS + kf;
          aH[i] = *(const f16x8*)&zbH[off];
          aL[i] = *(const f16x8*)&zbL[off];
        }
#pragma unroll
        for (int j = 0; j < 8; ++j) {
          size_t fo = (size_t)((wave * 8 + j) * 18 + kc) * 512 + lane * 8;
          f16x8 bH = *(const f16x8*)&FMoh[fo];
          f16x8 bL = *(const f16x8*)&FMol[fo];
#pragma unroll
          for (int i = 0; i < 2; ++i) {
            acc4[i][j] = __builtin_amdgcn_mfma_f32_16x16x32_f16(aH[i], bH, acc4[i][j], 0, 0, 0);
            acc4[i][j] = __builtin_amdgcn_mfma_f32_16x16x32_f16(aH[i], bL, acc4[i][j], 0, 0, 0);
            acc4[i][j] = __builtin_amdgcn_mfma_f32_16x16x32_f16(aL[i], bH, acc4[i][j], 0, 0, 0);
          }
        }
      }
      __syncthreads();  // all waves done reading old zb
#pragma unroll
      for (int j = 0; j < 8; ++j) {
        int col = wave * 128 + j * 16 + fr;
        float bb = dbo[col];
#pragma unroll
        for (int i = 0; i < 2; ++i)
#pragma unroll
          for (int r = 0; r < 4; ++r) {
            int row = i * 16 + rq * 4 + r;
            float v = fmaxf(acc4[i][j][r] + bb, 0.f);
            f16 hv = (f16)v;
            int po = row * ZS + (col ^ ((row & 7) << 3));
            zbH[po] = hv;
            zbL[po] = (f16)(v - (float)hv);
          }
      }
    }
  }
  if (lane == 0) entSh[wave] = entAcc;
  __syncthreads();
  if (tid == 0) atomicAdd(&out[32768], entSh[0] + entSh[1] + entSh[2] + entSh[3]);
  if (lane == 0) {
#pragma unroll
    for (int rr = 0; rr < 8; ++rr) out[32769 + b0 + wave * 8 + rr] = logpAcc[rr];
  }
}

// ---------------- host ----------------
extern "C" void kernel_launch(void* const* d_in, const int* in_sizes, int n_in,
                              void* d_out, int out_size, void* d_ws, size_t ws_size,
                              hipStream_t stream) {
  (void)in_sizes; (void)out_size; (void)ws_size;
  const float* actual = (const float*)d_in[0];
  const float* object = (const float*)d_in[1];
  const float* lastA = (const float*)d_in[2];
  const int* ep = (const int*)d_in[3];
  const float* W1 = (const float*)d_in[4];
  const float* b1 = (const float*)d_in[5];
  const float* W2 = (const float*)d_in[6];
  const float* b2 = (const float*)d_in[7];
  const float* W3 = (const float*)d_in[8];
  const float* b3 = (const float*)d_in[9];
  const float* Wih = (const float*)d_in[10];
  const float* Whh = (const float*)d_in[11];
  const float* bih = (const float*)d_in[12];
  const float* bhh = (const float*)d_in[13];
  const float* h0 = (const float*)d_in[14];
  const float* c0 = (const float*)d_in[15];
  const float* dW1 = (const float*)d_in[16];
  const float* db1 = (const float*)d_in[17];
  const float* headW[8];
  const float* headb[8];
  const float *dWo, *dbo;
  if (n_in >= 36) {
    for (int h = 0; h < 8; ++h) headW[h] = (const float*)d_in[18 + h];
    for (int h = 0; h < 8; ++h) headb[h] = (const float*)d_in[26 + h];
    dWo = (const float*)d_in[34];
    dbo = (const float*)d_in[35];
  } else {
    const float* hw = (const float*)d_in[18];
    const float* hbp = (const float*)d_in[19];
    for (int h = 0; h < 8; ++h) { headW[h] = hw + (size_t)h * 256 * 64; headb[h] = hbp + (size_t)h * 64; }
    dWo = (const float*)d_in[20];
    dbo = (const float*)d_in[21];
  }

  constexpr int Bq = 4096;
  constexpr int K1 = 9280, N1 = 3584, N1r = 3518;
  constexpr int K2 = 3584, N2 = 1408, N2r = 1342;
  constexpr int K3 = 1408, N3 = 512;
  constexpr int KL = 1024, NL = 2048;

  uint8_t* w = (uint8_t*)d_ws;
  size_t off = 0;
  auto alloc = [&](size_t bytes) -> void* {
    off = (off + 1023) & ~(size_t)1023;
    void* p = w + off;
    off += bytes;
    return p;
  };
  f16* A1h = (f16*)alloc((size_t)Bq * K1 * 2);
  f16* A1l = (f16*)alloc((size_t)Bq * K1 * 2);
  f16* Bt1h = (f16*)alloc((size_t)N1 * K1 * 2);
  f16* Bt1l = (f16*)alloc((size_t)N1 * K1 * 2);
  f16* x1h = (f16*)alloc((size_t)Bq * K2 * 2);
  f16* x1l = (f16*)alloc((size_t)Bq * K2 * 2);
  f16* Bt2h = (f16*)alloc((size_t)N2 * K2 * 2);
  f16* Bt2l = (f16*)alloc((size_t)N2 * K2 * 2);
  // pool aliases the A1 region (dead after GEMM1)
  size_t poff = 0;
  auto palloc = [&](size_t bytes) -> void* {
    poff = (poff + 1023) & ~(size_t)1023;
    void* p = w + poff;
    poff += bytes;
    return p;
  };
  f16* x2h = (f16*)palloc((size_t)Bq * K3 * 2);
  f16* x2l = (f16*)palloc((size_t)Bq * K3 * 2);
  f16* Bt3h = (f16*)palloc((size_t)N3 * K3 * 2);
  f16* Bt3l = (f16*)palloc((size_t)N3 * K3 * 2);
  f16* ALh = (f16*)palloc((size_t)Bq * KL * 2);
  f16* ALl = (f16*)palloc((size_t)Bq * KL * 2);
  f16* BLh = (f16*)palloc((size_t)NL * KL * 2);
  f16* BLl = (f16*)palloc((size_t)NL * KL * 2);
  float* gates = (float*)palloc((size_t)Bq * NL * 4);
  f16* zAH = (f16*)palloc((size_t)Bq * 576 * 2);
  f16* zAL = (f16*)palloc((size_t)Bq * 576 * 2);
  f16* FM1h = (f16*)palloc((size_t)16 * 16 * 512 * 2);
  f16* FM1l = (f16*)palloc((size_t)16 * 16 * 512 * 2);
  f16* FMhh = (f16*)palloc((size_t)8 * 32 * 512 * 2);
  f16* FMhl = (f16*)palloc((size_t)8 * 32 * 512 * 2);
  f16* FMoh = (f16*)palloc((size_t)32 * 18 * 512 * 2);
  f16* FMol = (f16*)palloc((size_t)32 * 18 * 512 * 2);

  // ---- subkeys (host, seed 42 only) ----
  uint32_t k0 = 0u, k1 = 42u;
  Keys8 sk;
  for (int h = 0; h < 8; ++h) {
    if (kPartitionable) {
      uint32_t a0, a1, b0v, b1v;
      tf2x32(k0, k1, 0u, 0u, a0, a1);
      tf2x32(k0, k1, 0u, 1u, b0v, b1v);
      sk.k[h][0] = b0v; sk.k[h][1] = b1v;
      k0 = a0; k1 = a1;
    } else {
      uint32_t a0, a1, b0v, b1v;
      tf2x32(k0, k1, 0u, 2u, a0, a1);
      tf2x32(k0, k1, 1u, 3u, b0v, b1v);
      sk.k[h][0] = a1; sk.k[h][1] = b1v;
      k0 = a0; k1 = b0v;
    }
  }
  Ptr8 hws, hbs;
  for (int h = 0; h < 8; ++h) { hws.p[h] = headW[h]; hbs.p[h] = headb[h]; }

  dim3 blk(256);
  dim3 tblk(32, 8);

  conv_feats<<<(4096u * 1160u + 255) / 256, blk, 0, stream>>>(actual, object, lastA, ep, A1h, A1l);
  convT_kernel<<<dim3(K1 / 32, N1 / 32), tblk, 0, stream>>>(W1, 9225, 3518, Bt1h, Bt1l, K1);
  convT_kernel<<<dim3(K2 / 32, N2 / 32), tblk, 0, stream>>>(W2, 3518, 1342, Bt2h, Bt2l, K2);

  gemm_split<128, 128><<<dim3(Bq / 128, N1 / 128), blk, 0, stream>>>(
      A1h, A1l, K1, Bt1h, Bt1l, K1, K1, b1, nullptr, N1r, 1, 0, nullptr, x1h, x1l, K2);

  // pool conversions (A1 dead now)
  init_pads<<<(4096u * 8u + 255) / 256, blk, 0, stream>>>(zAH, zAL, (float*)d_out);
  convT_kernel<<<dim3(K3 / 32, N3 / 32), tblk, 0, stream>>>(W3, 1342, 512, Bt3h, Bt3l, K3);
  conv_lstmB<<<(2048u * 1024u) / 256, blk, 0, stream>>>(Wih, Whh, BLh, BLl);
  conv_h0<<<(4096u * 512u) / 256, blk, 0, stream>>>(h0, ALh, ALl);
  conv_fm<<<(16 * 16 * 64 + 255) / 256, blk, 0, stream>>>(dW1, 512, 256, 16, 16, FM1h, FM1l);
  conv_fm<<<(32 * 18 * 64 + 255) / 256, blk, 0, stream>>>(dWo, 513, 512, 32, 18, FMoh, FMol);
  conv_fm_heads<<<dim3(8, 8), blk, 0, stream>>>(hws, FMhh, FMhl);

  gemm_split<128, 128><<<dim3(Bq / 128, N2 / 128), blk, 0, stream>>>(
      x1h, x1l, K2, Bt2h, Bt2l, K2, K2, b2, nullptr, N2r, 1, 0, nullptr, x2h, x2l, K3);
  gemm_split<128, 128><<<dim3(Bq / 128, N3 / 128), blk, 0, stream>>>(
      x2h, x2l, K3, Bt3h, Bt3l, K3, K3, b3, nullptr, N3, 1, 0, nullptr, ALh, ALl, KL);
  gemm_split<128, 128><<<dim3(Bq / 128, NL / 128), blk, 0, stream>>>(
      ALh, ALl, KL, BLh, BLl, KL, KL, bih, bhh, NL, 0, 1, gates, nullptr, nullptr, NL);
  lstm_pointwise<<<(4096u * 512u) / 256, blk, 0, stream>>>(gates, c0, zAH, zAL);

  decoder_fused<<<128, blk, 0, stream>>>(
      zAH, zAL, FM1h, FM1l, db1, FMhh, FMhl, hbs, FMoh, FMol, dbo,
      sk, kPartitionable, (float*)d_out);
}